// Round 9
// baseline (882.030 us; speedup 1.0000x reference)
//
#include <hip/hip_runtime.h>

// ---------------------------------------------------------------------------
// AGNN: h = relu(x@W1^T+b1); 4x [ h = relu(agnn(h)) ]; out = h@W2^T+b2
// N=100000, E=1600000, IN=128, HID=OUT=64, float32 in/out.
// Between layers: xn = h/(||h||+eps) stored FP16 (128 B/row) + nrm f32.
//   p = exp2( dot(xn_i * log2e, xn_j) );  out_i = sum p * nrm_j * xn_j / sum p
// agnn: nodes processed in DEGREE-SORTED order (perm) -> near-zero divergence;
//   4 nodes/wave (16 lanes each), 2 edge-groups x 8 lanes, unroll-2,
//   single-level group merge. f16 body: v_dot2_f32_f16 + v_pk_fma_f16.
// gemm1: 64-node blocks, K staged in four 32-chunks (16 KiB LDS -> 8 blk/CU).
// ---------------------------------------------------------------------------

typedef _Float16 h2 __attribute__((ext_vector_type(2)));

union U4H { uint4 u; h2 h[4]; };
union U2H { uint2 u; h2 h[2]; };
union UHI { unsigned u; h2 h; };

#define DEV_INLINE __device__ __forceinline__

DEV_INLINE h2 mkh2(float a, float b) {
    h2 r; r.x = (_Float16)a; r.y = (_Float16)b; return r;
}

__global__ __launch_bounds__(256) void build_rowptr(const int* __restrict__ row,
                                                    int* __restrict__ ptr,
                                                    int N, int E) {
    int i = blockIdx.x * blockDim.x + threadIdx.x;
    if (i > N) return;
    int lo = 0, hi = E;
    while (lo < hi) {
        int mid = (lo + hi) >> 1;
        if (row[mid] < i) lo = mid + 1; else hi = mid;
    }
    ptr[i] = lo;
}

// ---- degree-sorted permutation (4 tiny kernels) ---------------------------
__global__ __launch_bounds__(1024) void hist_zero(int* __restrict__ hist) {
    hist[threadIdx.x] = 0;
}

__global__ __launch_bounds__(256) void hist_build(const int* __restrict__ ptr,
                                                  int* __restrict__ hist, int N) {
    int i = blockIdx.x * blockDim.x + threadIdx.x;
    if (i >= N) return;
    int d = ptr[i + 1] - ptr[i];
    if (d > 1023) d = 1023;
    atomicAdd(&hist[d], 1);
}

__global__ __launch_bounds__(1024) void scan_hist(const int* __restrict__ hist,
                                                  int* __restrict__ offs) {
    __shared__ int a[1024], b[1024];
    const int t = threadIdx.x;
    const int h = hist[t];
    a[t] = h;
    __syncthreads();
    int* src = a; int* dst = b;
    for (int off = 1; off < 1024; off <<= 1) {
        int v = src[t] + (t >= off ? src[t - off] : 0);
        dst[t] = v;
        __syncthreads();
        int* tmp = src; src = dst; dst = tmp;
    }
    offs[t] = src[t] - h;   // exclusive prefix sum
}

__global__ __launch_bounds__(256) void scatter_perm(const int* __restrict__ ptr,
                                                    int* __restrict__ offs,
                                                    int* __restrict__ perm, int N) {
    int i = blockIdx.x * blockDim.x + threadIdx.x;
    if (i >= N) return;
    int d = ptr[i + 1] - ptr[i];
    if (d > 1023) d = 1023;
    int pos = atomicAdd(&offs[d], 1);
    perm[pos] = i;
}

// r = relu(x[i,:128]@W1^T + b1); xn[i]=f16(r/(||r||+eps)); nrm[i]=||r||+eps
__global__ __launch_bounds__(256) void gemm1_relu(const float* __restrict__ x,
                                                  const float* __restrict__ W1,
                                                  const float* __restrict__ b1,
                                                  unsigned short* __restrict__ xn,
                                                  float* __restrict__ nrm,
                                                  int N) {
    __shared__ __align__(16) float Wt[32 * 64];   // Wt[k*64+o], k in chunk
    __shared__ __align__(16) float xT[32 * 64];   // xT[k*64+m]
    const int tid  = threadIdx.x;
    const int tx   = tid & 15;
    const int ty   = tid >> 4;
    const int base = blockIdx.x * 64;

    float4 b4 = ((const float4*)b1)[tx];
    float4 acc[4];
    acc[0] = b4; acc[1] = b4; acc[2] = b4; acc[3] = b4;

    for (int kc = 0; kc < 128; kc += 32) {
        if (kc) __syncthreads();
        const float4* W4 = (const float4*)W1;
        for (int idx = tid; idx < 32 * 16; idx += 256) {
            int o = idx & 63, k4 = idx >> 6;          // k4 in [0,8)
            float4 v = W4[o * 32 + (kc >> 2) + k4];
            Wt[(4 * k4 + 0) * 64 + o] = v.x;
            Wt[(4 * k4 + 1) * 64 + o] = v.y;
            Wt[(4 * k4 + 2) * 64 + o] = v.z;
            Wt[(4 * k4 + 3) * 64 + o] = v.w;
        }
        const float4* x4p = (const float4*)x;
        for (int idx = tid; idx < 32 * 16; idx += 256) {
            int mm = idx & 63, k4 = idx >> 6;
            int node = base + mm;
            float4 v = make_float4(0.f, 0.f, 0.f, 0.f);
            if (node < N) v = x4p[(size_t)node * 32 + (kc >> 2) + k4];
            xT[(4 * k4 + 0) * 64 + mm] = v.x;
            xT[(4 * k4 + 1) * 64 + mm] = v.y;
            xT[(4 * k4 + 2) * 64 + mm] = v.z;
            xT[(4 * k4 + 3) * 64 + mm] = v.w;
        }
        __syncthreads();

#pragma unroll 4
        for (int k = 0; k < 32; ++k) {
            const float4 w4 = *(const float4*)&Wt[k * 64 + 4 * tx];
            const float4 xv = *(const float4*)&xT[k * 64 + 4 * ty];
            acc[0].x = fmaf(xv.x, w4.x, acc[0].x);
            acc[0].y = fmaf(xv.x, w4.y, acc[0].y);
            acc[0].z = fmaf(xv.x, w4.z, acc[0].z);
            acc[0].w = fmaf(xv.x, w4.w, acc[0].w);
            acc[1].x = fmaf(xv.y, w4.x, acc[1].x);
            acc[1].y = fmaf(xv.y, w4.y, acc[1].y);
            acc[1].z = fmaf(xv.y, w4.z, acc[1].z);
            acc[1].w = fmaf(xv.y, w4.w, acc[1].w);
            acc[2].x = fmaf(xv.z, w4.x, acc[2].x);
            acc[2].y = fmaf(xv.z, w4.y, acc[2].y);
            acc[2].z = fmaf(xv.z, w4.z, acc[2].z);
            acc[2].w = fmaf(xv.z, w4.w, acc[2].w);
            acc[3].x = fmaf(xv.w, w4.x, acc[3].x);
            acc[3].y = fmaf(xv.w, w4.y, acc[3].y);
            acc[3].z = fmaf(xv.w, w4.z, acc[3].z);
            acc[3].w = fmaf(xv.w, w4.w, acc[3].w);
        }
    }

#pragma unroll
    for (int mm = 0; mm < 4; ++mm) {
        float4 r = acc[mm];
        r.x = fmaxf(r.x, 0.f); r.y = fmaxf(r.y, 0.f);
        r.z = fmaxf(r.z, 0.f); r.w = fmaxf(r.w, 0.f);
        float s = fmaf(r.x, r.x, fmaf(r.y, r.y, fmaf(r.z, r.z, r.w * r.w)));
        s += __shfl_xor(s, 1, 64);
        s += __shfl_xor(s, 2, 64);
        s += __shfl_xor(s, 4, 64);
        s += __shfl_xor(s, 8, 64);
        const float nn  = sqrtf(s) + 1e-12f;
        const float inv = 1.f / nn;
        int node = base + 4 * ty + mm;
        if (node < N) {
            U2H pk;
            pk.h[0] = mkh2(r.x * inv, r.y * inv);
            pk.h[1] = mkh2(r.z * inv, r.w * inv);
            *(uint2*)&xn[(size_t)node * 64 + 4 * tx] = pk.u;
            if (tx == mm) nrm[node] = nn;
        }
    }
}

// 4 nodes per wave (16 lanes each, degree-sorted); 2 edge-groups x 8 lanes;
// 2 edges in flight per group.
__global__ __launch_bounds__(256) void agnn_layer(const uint4* __restrict__ xn4,
                                                  const float* __restrict__ nrm,
                                                  const int* __restrict__ ptr,
                                                  const int* __restrict__ col,
                                                  const int* __restrict__ perm,
                                                  uint4* __restrict__ xo4,
                                                  float* __restrict__ nrmo,
                                                  int N) {
    const int tid  = threadIdx.x;
    const int lane = tid & 63;
    const int g    = (lane >> 3) & 1;   // edge group 0..1 within 16-lane quarter
    const int sub  = lane & 7;          // 16B chunk of the 128B row
    const int slot = blockIdx.x * 16 + (tid >> 4);
    if (slot >= N) return;
    const int i = perm[slot];

    U4H hi_;
    hi_.u = xn4[(unsigned)i * 8u + sub];
    {
        const _Float16 L2E = (_Float16)1.4426950408889634f;
        h2 l2 = {L2E, L2E};
#pragma unroll
        for (int t = 0; t < 4; ++t) hi_.h[t] *= l2;   // p = exp2(dot)
    }

    const int p0 = ptr[i], p1 = ptr[i + 1];

    float den = 0.f;
    U4H acc;
    acc.h[0] = mkh2(0.f, 0.f); acc.h[1] = mkh2(0.f, 0.f);
    acc.h[2] = mkh2(0.f, 0.f); acc.h[3] = mkh2(0.f, 0.f);

#define EDGE_BODY(VU, NRMJ)                                                  \
    {                                                                        \
        U4H xa; xa.u = (VU);                                                 \
        float s = 0.f;                                                       \
        s = __builtin_amdgcn_fdot2(hi_.h[0], xa.h[0], s, false);             \
        s = __builtin_amdgcn_fdot2(hi_.h[1], xa.h[1], s, false);             \
        s = __builtin_amdgcn_fdot2(hi_.h[2], xa.h[2], s, false);             \
        s = __builtin_amdgcn_fdot2(hi_.h[3], xa.h[3], s, false);             \
        s += __shfl_xor(s, 1, 64);                                           \
        s += __shfl_xor(s, 2, 64);                                           \
        s += __shfl_xor(s, 4, 64);                                           \
        const float p = exp2f(s);                                            \
        den += p;                                                            \
        const _Float16 wh = (_Float16)(p * (NRMJ));                          \
        h2 w2 = {wh, wh};                                                    \
        acc.h[0] += w2 * xa.h[0];                                            \
        acc.h[1] += w2 * xa.h[1];                                            \
        acc.h[2] += w2 * xa.h[2];                                            \
        acc.h[3] += w2 * xa.h[3];                                            \
    }

    int e = p0 + g;
    for (; e + 2 < p1; e += 4) {          // 2 edges per group in flight
        const int ja = col[e];
        const int jb = col[e + 2];
        const uint4 va = xn4[(unsigned)ja * 8u + sub];
        const uint4 vb = xn4[(unsigned)jb * 8u + sub];
        const float na = nrm[ja];
        const float nb = nrm[jb];
        EDGE_BODY(va, na)
        EDGE_BODY(vb, nb)
    }
    if (e < p1) {
        const int j = col[e];
        const uint4 v = xn4[(unsigned)j * 8u + sub];
        const float nj = nrm[j];
        EDGE_BODY(v, nj)
    }
#undef EDGE_BODY

    // merge the 2 edge-groups (within the 16-lane quarter): xor 8
    {
        den += __shfl_xor(den, 8, 64);
#pragma unroll
        for (int t = 0; t < 4; ++t) {
            UHI a; a.h = acc.h[t];
            UHI b; b.u = (unsigned)__shfl_xor((int)a.u, 8, 64);
            acc.h[t] = a.h + b.h;
        }
    }

    const float id = 1.f / fmaxf(den, 1e-12f);
    float o[8];
#pragma unroll
    for (int t = 0; t < 4; ++t) {
        o[2 * t]     = fmaxf((float)acc.h[t].x * id, 0.f);
        o[2 * t + 1] = fmaxf((float)acc.h[t].y * id, 0.f);
    }

    float s2 = 0.f;
#pragma unroll
    for (int t = 0; t < 8; ++t) s2 = fmaf(o[t], o[t], s2);
    s2 += __shfl_xor(s2, 1, 64);
    s2 += __shfl_xor(s2, 2, 64);
    s2 += __shfl_xor(s2, 4, 64);
    const float nn  = sqrtf(s2) + 1e-12f;
    const float inv = 1.f / nn;

    if (g == 0) {
        U4H ov;
        ov.h[0] = mkh2(o[0] * inv, o[1] * inv);
        ov.h[1] = mkh2(o[2] * inv, o[3] * inv);
        ov.h[2] = mkh2(o[4] * inv, o[5] * inv);
        ov.h[3] = mkh2(o[6] * inv, o[7] * inv);
        xo4[(unsigned)i * 8u + sub] = ov.u;
        if (sub == 0) nrmo[i] = nn;
    }
}

// out[i,:64] = (xn[i]*nrm[i]) @ W2^T + b2   (f32 out)
__global__ __launch_bounds__(256) void gemm2(const unsigned short* __restrict__ xn,
                                             const float* __restrict__ nrm,
                                             const float* __restrict__ W2,
                                             const float* __restrict__ b2,
                                             float* __restrict__ out,
                                             int N) {
    __shared__ __align__(16) float Wt[64 * 64];
    __shared__ __align__(16) float xT[64 * 64];
    const int tid  = threadIdx.x;
    const int tx   = tid & 15;
    const int ty   = tid >> 4;
    const int base = blockIdx.x * 64;

    {
        const float4* W4 = (const float4*)W2;
        for (int idx = tid; idx < 64 * 16; idx += 256) {
            int o = idx & 63, k4 = idx >> 6;
            float4 v = W4[o * 16 + k4];
            Wt[(4 * k4 + 0) * 64 + o] = v.x;
            Wt[(4 * k4 + 1) * 64 + o] = v.y;
            Wt[(4 * k4 + 2) * 64 + o] = v.z;
            Wt[(4 * k4 + 3) * 64 + o] = v.w;
        }
        const uint2* x2 = (const uint2*)xn;
        for (int idx = tid; idx < 64 * 16; idx += 256) {
            int mm = idx & 63, k4 = idx >> 6;
            int node = base + mm;
            U2H v; v.u = make_uint2(0u, 0u);
            float nn = 0.f;
            if (node < N) { v.u = x2[(size_t)node * 16 + k4]; nn = nrm[node]; }
            xT[(4 * k4 + 0) * 64 + mm] = (float)v.h[0].x * nn;
            xT[(4 * k4 + 1) * 64 + mm] = (float)v.h[0].y * nn;
            xT[(4 * k4 + 2) * 64 + mm] = (float)v.h[1].x * nn;
            xT[(4 * k4 + 3) * 64 + mm] = (float)v.h[1].y * nn;
        }
    }
    __syncthreads();

    float4 b4 = ((const float4*)b2)[tx];
    float4 acc[4];
    acc[0] = b4; acc[1] = b4; acc[2] = b4; acc[3] = b4;

#pragma unroll 4
    for (int k = 0; k < 64; ++k) {
        const float4 w4 = *(const float4*)&Wt[k * 64 + 4 * tx];
        const float4 xv = *(const float4*)&xT[k * 64 + 4 * ty];
        acc[0].x = fmaf(xv.x, w4.x, acc[0].x);
        acc[0].y = fmaf(xv.x, w4.y, acc[0].y);
        acc[0].z = fmaf(xv.x, w4.z, acc[0].z);
        acc[0].w = fmaf(xv.x, w4.w, acc[0].w);
        acc[1].x = fmaf(xv.y, w4.x, acc[1].x);
        acc[1].y = fmaf(xv.y, w4.y, acc[1].y);
        acc[1].z = fmaf(xv.y, w4.z, acc[1].z);
        acc[1].w = fmaf(xv.y, w4.w, acc[1].w);
        acc[2].x = fmaf(xv.z, w4.x, acc[2].x);
        acc[2].y = fmaf(xv.z, w4.y, acc[2].y);
        acc[2].z = fmaf(xv.z, w4.z, acc[2].z);
        acc[2].w = fmaf(xv.z, w4.w, acc[2].w);
        acc[3].x = fmaf(xv.w, w4.x, acc[3].x);
        acc[3].y = fmaf(xv.w, w4.y, acc[3].y);
        acc[3].z = fmaf(xv.w, w4.z, acc[3].z);
        acc[3].w = fmaf(xv.w, w4.w, acc[3].w);
    }

#pragma unroll
    for (int mm = 0; mm < 4; ++mm) {
        int node = base + 4 * ty + mm;
        if (node < N) *(float4*)&out[(size_t)node * 64 + 4 * tx] = acc[mm];
    }
}

extern "C" void kernel_launch(void* const* d_in, const int* in_sizes, int n_in,
                              void* d_out, int out_size, void* d_ws, size_t ws_size,
                              hipStream_t stream) {
    const float* x   = (const float*)d_in[0];
    const int*   row = (const int*)d_in[1];
    const int*   col = (const int*)d_in[2];
    const float* W1  = (const float*)d_in[3];
    const float* b1  = (const float*)d_in[4];
    const float* W2  = (const float*)d_in[5];
    const float* b2  = (const float*)d_in[6];
    float* out = (float*)d_out;

    const int N = in_sizes[0] / 128;
    const int E = in_sizes[1];

    char* ws = (char*)d_ws;
    size_t off = 0;
    unsigned short* ha = (unsigned short*)(ws + off); off += (size_t)N * 64 * 2;
    unsigned short* hb = (unsigned short*)(ws + off); off += (size_t)N * 64 * 2;
    float* na_  = (float*)(ws + off); off += (size_t)N * sizeof(float);
    float* nb_  = (float*)(ws + off); off += (size_t)N * sizeof(float);
    int*   ptr  = (int*)  (ws + off); off += (size_t)(N + 1) * sizeof(int);
    off = (off + 15) & ~(size_t)15;
    int*   hist = (int*)  (ws + off); off += 1024 * sizeof(int);
    int*   offs = (int*)  (ws + off); off += 1024 * sizeof(int);
    int*   perm = (int*)  (ws + off); off += (size_t)N * sizeof(int);
    (void)ws_size; (void)n_in; (void)out_size;

    build_rowptr<<<(N + 256) / 256, 256, 0, stream>>>(row, ptr, N, E);

    // degree-sorted node permutation (divergence-free agnn waves)
    hist_zero<<<1, 1024, 0, stream>>>(hist);
    hist_build<<<(N + 255) / 256, 256, 0, stream>>>(ptr, hist, N);
    scan_hist<<<1, 1024, 0, stream>>>(hist, offs);
    scatter_perm<<<(N + 255) / 256, 256, 0, stream>>>(ptr, offs, perm, N);

    const int nbG = (N + 63) / 64;
    gemm1_relu<<<nbG, 256, 0, stream>>>(x, W1, b1, ha, na_, N);

    const int nb16 = (N + 15) / 16;
    unsigned short* hc = ha; unsigned short* hn = hb;
    float* nc = na_; float* nn = nb_;
    for (int l = 0; l < 4; ++l) {
        agnn_layer<<<nb16, 256, 0, stream>>>((const uint4*)hc, nc, ptr, col, perm,
                                             (uint4*)hn, nn, N);
        unsigned short* t = hc; hc = hn; hn = t;
        float* tf = nc; nc = nn; nn = tf;
    }

    gemm2<<<nbG, 256, 0, stream>>>(hc, nc, W2, b2, out, N);
}

// Round 10
// 300.715 us; speedup vs baseline: 2.9331x; 2.9331x over previous
//
#include <hip/hip_runtime.h>

// ---------------------------------------------------------------------------
// AGNN: h = relu(x@W1^T+b1); 4x [ h = relu(agnn(h)) ]; out = h@W2^T+b2
// N=100000, E=1600000, IN=128, HID=OUT=64, float32 in/out.
// Between layers: xn = h/(||h||+eps) stored FP16 (128 B/row) + nrm f32.
//   p = exp2( dot(xn_i * log2e, xn_j) );  out_i = sum p * nrm_j * xn_j / sum p
// agnn: nodes processed in SEGMENT-LOCAL degree-sorted order (perm):
//   one workgroup counting-sorts each 8192-node segment in LDS (no global
//   atomics — round 9's global-atomic hist/scatter was a 550 us disaster).
//   4 nodes/wave (16 lanes each), 2 edge-groups x 8 lanes, unroll-2,
//   single-level group merge. f16 body: v_dot2_f32_f16 + v_pk_fma_f16.
// gemm1: 64-node blocks, K staged in four 32-chunks (16 KiB LDS -> 8 blk/CU).
// ---------------------------------------------------------------------------

typedef _Float16 h2 __attribute__((ext_vector_type(2)));

union U4H { uint4 u; h2 h[4]; };
union U2H { uint2 u; h2 h[2]; };
union UHI { unsigned u; h2 h; };

#define DEV_INLINE __device__ __forceinline__

DEV_INLINE h2 mkh2(float a, float b) {
    h2 r; r.x = (_Float16)a; r.y = (_Float16)b; return r;
}

__global__ __launch_bounds__(256) void build_rowptr(const int* __restrict__ row,
                                                    int* __restrict__ ptr,
                                                    int N, int E) {
    int i = blockIdx.x * blockDim.x + threadIdx.x;
    if (i > N) return;
    int lo = 0, hi = E;
    while (lo < hi) {
        int mid = (lo + hi) >> 1;
        if (row[mid] < i) lo = mid + 1; else hi = mid;
    }
    ptr[i] = lo;
}

// Segment-local counting sort by degree. One 1024-thread block per 8192-node
// segment; LDS histogram + LDS scan + LDS-atomic rank scatter. perm[] is a
// permutation of [0,N) where each segment's slots are degree-sorted.
#define SEG 8192
__global__ __launch_bounds__(1024) void build_perm_seg(const int* __restrict__ ptr,
                                                       int* __restrict__ perm,
                                                       int N) {
    __shared__ int a[1024], b[1024];
    const int t    = threadIdx.x;
    const int base = blockIdx.x * SEG;
    const int end  = (base + SEG < N) ? base + SEG : N;

    a[t] = 0;
    __syncthreads();
    for (int i = base + t; i < end; i += 1024) {
        int d = ptr[i + 1] - ptr[i];
        if (d > 1023) d = 1023;
        atomicAdd(&a[d], 1);
    }
    __syncthreads();

    // Hillis-Steele inclusive scan over a[], ping-pong with b[]
    const int h = a[t];
    int* src = a; int* dst = b;
    for (int off = 1; off < 1024; off <<= 1) {
        int v = src[t] + (t >= off ? src[t - off] : 0);
        dst[t] = v;
        __syncthreads();
        int* tmp = src; src = dst; dst = tmp;
    }
    // 10 iterations -> src == a. Convert to exclusive offsets in-place.
    src[t] = src[t] - h;
    __syncthreads();

    for (int i = base + t; i < end; i += 1024) {
        int d = ptr[i + 1] - ptr[i];
        if (d > 1023) d = 1023;
        int pos = base + atomicAdd(&src[d], 1);
        perm[pos] = i;
    }
}

// r = relu(x[i,:128]@W1^T + b1); xn[i]=f16(r/(||r||+eps)); nrm[i]=||r||+eps
__global__ __launch_bounds__(256) void gemm1_relu(const float* __restrict__ x,
                                                  const float* __restrict__ W1,
                                                  const float* __restrict__ b1,
                                                  unsigned short* __restrict__ xn,
                                                  float* __restrict__ nrm,
                                                  int N) {
    __shared__ __align__(16) float Wt[32 * 64];   // Wt[k*64+o], k in chunk
    __shared__ __align__(16) float xT[32 * 64];   // xT[k*64+m]
    const int tid  = threadIdx.x;
    const int tx   = tid & 15;
    const int ty   = tid >> 4;
    const int base = blockIdx.x * 64;

    float4 b4 = ((const float4*)b1)[tx];
    float4 acc[4];
    acc[0] = b4; acc[1] = b4; acc[2] = b4; acc[3] = b4;

    for (int kc = 0; kc < 128; kc += 32) {
        if (kc) __syncthreads();
        const float4* W4 = (const float4*)W1;
        for (int idx = tid; idx < 32 * 16; idx += 256) {
            int o = idx & 63, k4 = idx >> 6;          // k4 in [0,8)
            float4 v = W4[o * 32 + (kc >> 2) + k4];
            Wt[(4 * k4 + 0) * 64 + o] = v.x;
            Wt[(4 * k4 + 1) * 64 + o] = v.y;
            Wt[(4 * k4 + 2) * 64 + o] = v.z;
            Wt[(4 * k4 + 3) * 64 + o] = v.w;
        }
        const float4* x4p = (const float4*)x;
        for (int idx = tid; idx < 32 * 16; idx += 256) {
            int mm = idx & 63, k4 = idx >> 6;
            int node = base + mm;
            float4 v = make_float4(0.f, 0.f, 0.f, 0.f);
            if (node < N) v = x4p[(size_t)node * 32 + (kc >> 2) + k4];
            xT[(4 * k4 + 0) * 64 + mm] = v.x;
            xT[(4 * k4 + 1) * 64 + mm] = v.y;
            xT[(4 * k4 + 2) * 64 + mm] = v.z;
            xT[(4 * k4 + 3) * 64 + mm] = v.w;
        }
        __syncthreads();

#pragma unroll 4
        for (int k = 0; k < 32; ++k) {
            const float4 w4 = *(const float4*)&Wt[k * 64 + 4 * tx];
            const float4 xv = *(const float4*)&xT[k * 64 + 4 * ty];
            acc[0].x = fmaf(xv.x, w4.x, acc[0].x);
            acc[0].y = fmaf(xv.x, w4.y, acc[0].y);
            acc[0].z = fmaf(xv.x, w4.z, acc[0].z);
            acc[0].w = fmaf(xv.x, w4.w, acc[0].w);
            acc[1].x = fmaf(xv.y, w4.x, acc[1].x);
            acc[1].y = fmaf(xv.y, w4.y, acc[1].y);
            acc[1].z = fmaf(xv.y, w4.z, acc[1].z);
            acc[1].w = fmaf(xv.y, w4.w, acc[1].w);
            acc[2].x = fmaf(xv.z, w4.x, acc[2].x);
            acc[2].y = fmaf(xv.z, w4.y, acc[2].y);
            acc[2].z = fmaf(xv.z, w4.z, acc[2].z);
            acc[2].w = fmaf(xv.z, w4.w, acc[2].w);
            acc[3].x = fmaf(xv.w, w4.x, acc[3].x);
            acc[3].y = fmaf(xv.w, w4.y, acc[3].y);
            acc[3].z = fmaf(xv.w, w4.z, acc[3].z);
            acc[3].w = fmaf(xv.w, w4.w, acc[3].w);
        }
    }

#pragma unroll
    for (int mm = 0; mm < 4; ++mm) {
        float4 r = acc[mm];
        r.x = fmaxf(r.x, 0.f); r.y = fmaxf(r.y, 0.f);
        r.z = fmaxf(r.z, 0.f); r.w = fmaxf(r.w, 0.f);
        float s = fmaf(r.x, r.x, fmaf(r.y, r.y, fmaf(r.z, r.z, r.w * r.w)));
        s += __shfl_xor(s, 1, 64);
        s += __shfl_xor(s, 2, 64);
        s += __shfl_xor(s, 4, 64);
        s += __shfl_xor(s, 8, 64);
        const float nn  = sqrtf(s) + 1e-12f;
        const float inv = 1.f / nn;
        int node = base + 4 * ty + mm;
        if (node < N) {
            U2H pk;
            pk.h[0] = mkh2(r.x * inv, r.y * inv);
            pk.h[1] = mkh2(r.z * inv, r.w * inv);
            *(uint2*)&xn[(size_t)node * 64 + 4 * tx] = pk.u;
            if (tx == mm) nrm[node] = nn;
        }
    }
}

// 4 nodes per wave (16 lanes each, degree-sorted); 2 edge-groups x 8 lanes;
// 2 edges in flight per group.
__global__ __launch_bounds__(256) void agnn_layer(const uint4* __restrict__ xn4,
                                                  const float* __restrict__ nrm,
                                                  const int* __restrict__ ptr,
                                                  const int* __restrict__ col,
                                                  const int* __restrict__ perm,
                                                  uint4* __restrict__ xo4,
                                                  float* __restrict__ nrmo,
                                                  int N) {
    const int tid  = threadIdx.x;
    const int lane = tid & 63;
    const int g    = (lane >> 3) & 1;   // edge group 0..1 within 16-lane quarter
    const int sub  = lane & 7;          // 16B chunk of the 128B row
    const int slot = blockIdx.x * 16 + (tid >> 4);
    if (slot >= N) return;
    const int i = perm[slot];

    U4H hi_;
    hi_.u = xn4[(unsigned)i * 8u + sub];
    {
        const _Float16 L2E = (_Float16)1.4426950408889634f;
        h2 l2 = {L2E, L2E};
#pragma unroll
        for (int t = 0; t < 4; ++t) hi_.h[t] *= l2;   // p = exp2(dot)
    }

    const int p0 = ptr[i], p1 = ptr[i + 1];

    float den = 0.f;
    U4H acc;
    acc.h[0] = mkh2(0.f, 0.f); acc.h[1] = mkh2(0.f, 0.f);
    acc.h[2] = mkh2(0.f, 0.f); acc.h[3] = mkh2(0.f, 0.f);

#define EDGE_BODY(VU, NRMJ)                                                  \
    {                                                                        \
        U4H xa; xa.u = (VU);                                                 \
        float s = 0.f;                                                       \
        s = __builtin_amdgcn_fdot2(hi_.h[0], xa.h[0], s, false);             \
        s = __builtin_amdgcn_fdot2(hi_.h[1], xa.h[1], s, false);             \
        s = __builtin_amdgcn_fdot2(hi_.h[2], xa.h[2], s, false);             \
        s = __builtin_amdgcn_fdot2(hi_.h[3], xa.h[3], s, false);             \
        s += __shfl_xor(s, 1, 64);                                           \
        s += __shfl_xor(s, 2, 64);                                           \
        s += __shfl_xor(s, 4, 64);                                           \
        const float p = exp2f(s);                                            \
        den += p;                                                            \
        const _Float16 wh = (_Float16)(p * (NRMJ));                          \
        h2 w2 = {wh, wh};                                                    \
        acc.h[0] += w2 * xa.h[0];                                            \
        acc.h[1] += w2 * xa.h[1];                                            \
        acc.h[2] += w2 * xa.h[2];                                            \
        acc.h[3] += w2 * xa.h[3];                                            \
    }

    int e = p0 + g;
    for (; e + 2 < p1; e += 4) {          // 2 edges per group in flight
        const int ja = col[e];
        const int jb = col[e + 2];
        const uint4 va = xn4[(unsigned)ja * 8u + sub];
        const uint4 vb = xn4[(unsigned)jb * 8u + sub];
        const float na = nrm[ja];
        const float nb = nrm[jb];
        EDGE_BODY(va, na)
        EDGE_BODY(vb, nb)
    }
    if (e < p1) {
        const int j = col[e];
        const uint4 v = xn4[(unsigned)j * 8u + sub];
        const float nj = nrm[j];
        EDGE_BODY(v, nj)
    }
#undef EDGE_BODY

    // merge the 2 edge-groups (within the 16-lane quarter): xor 8
    {
        den += __shfl_xor(den, 8, 64);
#pragma unroll
        for (int t = 0; t < 4; ++t) {
            UHI a; a.h = acc.h[t];
            UHI b; b.u = (unsigned)__shfl_xor((int)a.u, 8, 64);
            acc.h[t] = a.h + b.h;
        }
    }

    const float id = 1.f / fmaxf(den, 1e-12f);
    float o[8];
#pragma unroll
    for (int t = 0; t < 4; ++t) {
        o[2 * t]     = fmaxf((float)acc.h[t].x * id, 0.f);
        o[2 * t + 1] = fmaxf((float)acc.h[t].y * id, 0.f);
    }

    float s2 = 0.f;
#pragma unroll
    for (int t = 0; t < 8; ++t) s2 = fmaf(o[t], o[t], s2);
    s2 += __shfl_xor(s2, 1, 64);
    s2 += __shfl_xor(s2, 2, 64);
    s2 += __shfl_xor(s2, 4, 64);
    const float nn  = sqrtf(s2) + 1e-12f;
    const float inv = 1.f / nn;

    if (g == 0) {
        U4H ov;
        ov.h[0] = mkh2(o[0] * inv, o[1] * inv);
        ov.h[1] = mkh2(o[2] * inv, o[3] * inv);
        ov.h[2] = mkh2(o[4] * inv, o[5] * inv);
        ov.h[3] = mkh2(o[6] * inv, o[7] * inv);
        xo4[(unsigned)i * 8u + sub] = ov.u;
        if (sub == 0) nrmo[i] = nn;
    }
}

// out[i,:64] = (xn[i]*nrm[i]) @ W2^T + b2   (f32 out)
__global__ __launch_bounds__(256) void gemm2(const unsigned short* __restrict__ xn,
                                             const float* __restrict__ nrm,
                                             const float* __restrict__ W2,
                                             const float* __restrict__ b2,
                                             float* __restrict__ out,
                                             int N) {
    __shared__ __align__(16) float Wt[64 * 64];
    __shared__ __align__(16) float xT[64 * 64];
    const int tid  = threadIdx.x;
    const int tx   = tid & 15;
    const int ty   = tid >> 4;
    const int base = blockIdx.x * 64;

    {
        const float4* W4 = (const float4*)W2;
        for (int idx = tid; idx < 64 * 16; idx += 256) {
            int o = idx & 63, k4 = idx >> 6;
            float4 v = W4[o * 16 + k4];
            Wt[(4 * k4 + 0) * 64 + o] = v.x;
            Wt[(4 * k4 + 1) * 64 + o] = v.y;
            Wt[(4 * k4 + 2) * 64 + o] = v.z;
            Wt[(4 * k4 + 3) * 64 + o] = v.w;
        }
        const uint2* x2 = (const uint2*)xn;
        for (int idx = tid; idx < 64 * 16; idx += 256) {
            int mm = idx & 63, k4 = idx >> 6;
            int node = base + mm;
            U2H v; v.u = make_uint2(0u, 0u);
            float nn = 0.f;
            if (node < N) { v.u = x2[(size_t)node * 16 + k4]; nn = nrm[node]; }
            xT[(4 * k4 + 0) * 64 + mm] = (float)v.h[0].x * nn;
            xT[(4 * k4 + 1) * 64 + mm] = (float)v.h[0].y * nn;
            xT[(4 * k4 + 2) * 64 + mm] = (float)v.h[1].x * nn;
            xT[(4 * k4 + 3) * 64 + mm] = (float)v.h[1].y * nn;
        }
    }
    __syncthreads();

    float4 b4 = ((const float4*)b2)[tx];
    float4 acc[4];
    acc[0] = b4; acc[1] = b4; acc[2] = b4; acc[3] = b4;

#pragma unroll 4
    for (int k = 0; k < 64; ++k) {
        const float4 w4 = *(const float4*)&Wt[k * 64 + 4 * tx];
        const float4 xv = *(const float4*)&xT[k * 64 + 4 * ty];
        acc[0].x = fmaf(xv.x, w4.x, acc[0].x);
        acc[0].y = fmaf(xv.x, w4.y, acc[0].y);
        acc[0].z = fmaf(xv.x, w4.z, acc[0].z);
        acc[0].w = fmaf(xv.x, w4.w, acc[0].w);
        acc[1].x = fmaf(xv.y, w4.x, acc[1].x);
        acc[1].y = fmaf(xv.y, w4.y, acc[1].y);
        acc[1].z = fmaf(xv.y, w4.z, acc[1].z);
        acc[1].w = fmaf(xv.y, w4.w, acc[1].w);
        acc[2].x = fmaf(xv.z, w4.x, acc[2].x);
        acc[2].y = fmaf(xv.z, w4.y, acc[2].y);
        acc[2].z = fmaf(xv.z, w4.z, acc[2].z);
        acc[2].w = fmaf(xv.z, w4.w, acc[2].w);
        acc[3].x = fmaf(xv.w, w4.x, acc[3].x);
        acc[3].y = fmaf(xv.w, w4.y, acc[3].y);
        acc[3].z = fmaf(xv.w, w4.z, acc[3].z);
        acc[3].w = fmaf(xv.w, w4.w, acc[3].w);
    }

#pragma unroll
    for (int mm = 0; mm < 4; ++mm) {
        int node = base + 4 * ty + mm;
        if (node < N) *(float4*)&out[(size_t)node * 64 + 4 * tx] = acc[mm];
    }
}

extern "C" void kernel_launch(void* const* d_in, const int* in_sizes, int n_in,
                              void* d_out, int out_size, void* d_ws, size_t ws_size,
                              hipStream_t stream) {
    const float* x   = (const float*)d_in[0];
    const int*   row = (const int*)d_in[1];
    const int*   col = (const int*)d_in[2];
    const float* W1  = (const float*)d_in[3];
    const float* b1  = (const float*)d_in[4];
    const float* W2  = (const float*)d_in[5];
    const float* b2  = (const float*)d_in[6];
    float* out = (float*)d_out;

    const int N = in_sizes[0] / 128;
    const int E = in_sizes[1];

    char* ws = (char*)d_ws;
    size_t off = 0;
    unsigned short* ha = (unsigned short*)(ws + off); off += (size_t)N * 64 * 2;
    unsigned short* hb = (unsigned short*)(ws + off); off += (size_t)N * 64 * 2;
    float* na_  = (float*)(ws + off); off += (size_t)N * sizeof(float);
    float* nb_  = (float*)(ws + off); off += (size_t)N * sizeof(float);
    int*   ptr  = (int*)  (ws + off); off += (size_t)(N + 1) * sizeof(int);
    off = (off + 15) & ~(size_t)15;
    int*   perm = (int*)  (ws + off); off += (size_t)N * sizeof(int);
    (void)ws_size; (void)n_in; (void)out_size;

    build_rowptr<<<(N + 256) / 256, 256, 0, stream>>>(row, ptr, N, E);

    // segment-local degree sort (all atomics in LDS)
    build_perm_seg<<<(N + SEG - 1) / SEG, 1024, 0, stream>>>(ptr, perm, N);

    const int nbG = (N + 63) / 64;
    gemm1_relu<<<nbG, 256, 0, stream>>>(x, W1, b1, ha, na_, N);

    const int nb16 = (N + 15) / 16;
    unsigned short* hc = ha; unsigned short* hn = hb;
    float* nc = na_; float* nn = nb_;
    for (int l = 0; l < 4; ++l) {
        agnn_layer<<<nb16, 256, 0, stream>>>((const uint4*)hc, nc, ptr, col, perm,
                                             (uint4*)hn, nn, N);
        unsigned short* t = hc; hc = hn; hn = t;
        float* tf = nc; nc = nn; nn = tf;
    }

    gemm2<<<nbG, 256, 0, stream>>>(hc, nc, W2, b2, out, N);
}